// Round 3
// baseline (595.409 us; speedup 1.0000x reference)
//
#include <hip/hip_runtime.h>
#include <math.h>

// Problem constants (mirroring the reference)
#define IMG_H 480
#define IMG_W 640
#define DU    4
#define SUB_H 120          // IMG_H / DU
#define SUB_W 160          // IMG_W / DU
#define NPIX  (SUB_H * SUB_W)   // 19200
#define NSEM  16
#define NCH_IN 20          // 4 + NSEM input channels
#define VR    100
#define ZBINS 80           // MAX_VOX - MIN_VOX = 72 - (-8)
#define MIN_MAPPED 13      // 25/5 - (-8)
#define MAX_MAPPED 25      // int(89/5) - (-8)
#define NOUT  18           // 2 + NSEM
#define NCELL (VR * VR)    // 10000
#define NJOBS 16           // one job per sem channel; job0 also agent, job1 also explored
#define BLOCK 1024
#define NSLICE 16          // phase-A slices per frame

#define REC_VALID (1 << 16)
#define REC_AGENT (1 << 17)

// Two-phase structure. The old single kernel recomputed the per-pixel depth
// binning (5 correctly-rounded fp32 divides + 3 rintf, ~65 VALU ops) in EVERY
// one of the 16 jobs per frame -- the dominant VALU term. Phase A computes it
// ONCE per frame (bit-exact op order, true divisions, rintf = round-nearest-
// even) and emits a compact record per pixel into the workspace:
//   rec = cell(0..9999) | VALID | AGENT(zb in agent band)
// Phase B (one block per frame x sem channel) reads records COALESCED
// (replacing the strided depth re-read entirely), loads its sem channel (nt:
// single-use stream, keep L2 for reused lines), and scatters into a 40 KB LDS
// grid. MAP_T = EXP_T = 1.0 and counts are integers, so agent/explored grids
// are binary after clip: racy plain 1.0f stores, no atomics. Sem sums keep
// LDS atomicAdd. Frame-major block decode keeps a frame's jobs on one XCD.

__global__ __launch_bounds__(BLOCK, 1)
void binning_kernel(const float* __restrict__ obs,
                    int* __restrict__ recs,
                    float f_pix, int nframes) {
    const int f = blockIdx.x % nframes;       // frame-major -> XCD locality
    const int s = blockIdx.x / nframes;       // slice 0..NSLICE-1
    const int tid = threadIdx.x;

    const float* depth_ch = obs + ((size_t)f * NCH_IN + 3) * IMG_H * IMG_W;
    int* rec = recs + (size_t)f * NPIX;

    const int p0 = s * (NPIX / NSLICE);       // 1200 pixels per slice
    const int p1 = p0 + NPIX / NSLICE;

    for (int p = p0 + tid; p < p1; p += BLOCK) {
        int v = p / SUB_W;
        int u = p - v * SUB_W;
        size_t pix = (size_t)(v * DU) * IMG_W + (size_t)(u * DU);

        float depth = depth_ch[pix];
        int r = 0;
        if (depth > 20.0f && depth < 500.0f) {
            // Match the np reference's fp32 op order exactly (true divisions
            // -- no reciprocal rewrite, binning must be bit-exact).
            float uu = (float)(u * DU);
            float vv = (float)(v * DU);
            float X  = (uu - 320.0f) * depth / f_pix;
            float Zh = 88.0f + (240.0f - vv) * depth / f_pix;

            // np.round is half-to-even; rintf honors round-nearest-even.
            int xb = (int)rintf(X / 5.0f + 50.0f);
            int yb = (int)rintf(depth / 5.0f);
            int zb = (int)rintf(Zh / 5.0f) + 8;   // - MIN_VOX (= -8)

            if (xb >= 0 && xb < VR && yb >= 0 && yb < VR &&
                zb >= 0 && zb < ZBINS) {
                r = (yb * VR + xb) | REC_VALID;
                if (zb >= MIN_MAPPED && zb < MAX_MAPPED) r |= REC_AGENT;
            }
        }
        rec[p] = r;   // unconditional: workspace is poisoned every iteration
    }
}

__global__ __launch_bounds__(BLOCK, 1)
void scatter_kernel(const float* __restrict__ obs,
                    const int* __restrict__ recs,
                    float* __restrict__ out,
                    int nframes) {
    __shared__ float acc[NCELL];        // sem grid for this job's channel
    __shared__ float acc2[NCELL];       // job0: agent grid; job1: explored grid

    const int f = blockIdx.x % nframes;   // frame-major -> same-XCD per frame
    const int j = blockIdx.x / nframes;   // sem channel / job id
    const int tid = threadIdx.x;

    for (int c = tid; c < NCELL; c += BLOCK) acc[c] = 0.0f;
    if (j < 2)
        for (int c = tid; c < NCELL; c += BLOCK) acc2[c] = 0.0f;
    __syncthreads();

    const float* sem_ch = obs + ((size_t)f * NCH_IN + 4 + j) * IMG_H * IMG_W;
    const int* rec = recs + (size_t)f * NPIX;

    for (int p = tid; p < NPIX; p += BLOCK) {
        int r = rec[p];                     // coalesced, L2-resident (16x reuse)
        if (!(r & REC_VALID)) continue;

        int v = p / SUB_W;
        int u = p - v * SUB_W;
        size_t pix = (size_t)(v * DU) * IMG_W + (size_t)(u * DU);

        int cell = r & 0xFFFF;
        float s = __builtin_nontemporal_load(sem_ch + pix);
        atomicAdd(&acc[cell], s);                     // sem channel j sum
        if (j == 0) {
            if (r & REC_AGENT)
                acc2[cell] = 1.0f;                    // agent grid (binary)
        } else if (j == 1) {
            acc2[cell] = 1.0f;                        // explored grid (binary)
        }
    }
    __syncthreads();

    float* outf = out + (size_t)f * NOUT * NCELL;

    // sem channel -> out ch 2+j
    {
        float* oc = outf + (size_t)(2 + j) * NCELL;
        for (int c = tid; c < NCELL; c += BLOCK) {
            float val = fminf(fmaxf(acc[c] / 5.0f, 0.0f), 1.0f);
            __builtin_nontemporal_store(val, oc + c);
        }
    }

    if (j == 0) {
        // 3x3 max-dilate the (binary) agent grid from LDS, then clip.
        for (int c = tid; c < NCELL; c += BLOCK) {
            int y = c / VR;
            int x = c - y * VR;
            float m = 0.0f;
            int y0 = (y > 0) ? y - 1 : 0, y1 = (y < VR - 1) ? y + 1 : VR - 1;
            int x0 = (x > 0) ? x - 1 : 0, x1 = (x < VR - 1) ? x + 1 : VR - 1;
            for (int yy = y0; yy <= y1; ++yy)
                for (int xx = x0; xx <= x1; ++xx)
                    m = fmaxf(m, acc2[yy * VR + xx]);
            __builtin_nontemporal_store(fminf(m, 1.0f), outf + c);   // obstacle
        }
    } else if (j == 1) {
        for (int c = tid; c < NCELL; c += BLOCK) {
            float val = fminf(fmaxf(acc2[c], 0.0f), 1.0f);
            __builtin_nontemporal_store(val, outf + NCELL + c);      // explored
        }
    }
}

extern "C" void kernel_launch(void* const* d_in, const int* in_sizes, int n_in,
                              void* d_out, int out_size, void* d_ws, size_t ws_size,
                              hipStream_t stream) {
    const float* obs = (const float*)d_in[0];
    float* out = (float*)d_out;
    int* recs = (int*)d_ws;   // 16 frames * 19200 recs * 4 B = 1.23 MB

    int nframes = in_sizes[0] / (NCH_IN * IMG_H * IMG_W);   // B*T = 16

    // F_PIX = W/2 / tan(deg2rad(HFOV/2)) in double like numpy, then fp32.
    float f_pix = (float)(IMG_W / 2.0 / tan((79.0 / 2.0) * M_PI / 180.0));

    binning_kernel<<<nframes * NSLICE, BLOCK, 0, stream>>>(obs, recs, f_pix, nframes);
    scatter_kernel<<<nframes * NJOBS, BLOCK, 0, stream>>>(obs, recs, out, nframes);
}